// Round 5
// baseline (330.707 us; speedup 1.0000x reference)
//
#include <hip/hip_runtime.h>
#include <hip/hip_bf16.h>
#include <hip/hip_fp16.h>

#define HCH 4      // heads
#define F   128    // H*C
#define DIN 128
#define HID 128
#define NEG 0.2f
#define L2E 1.4426950408889634f

typedef _Float16 hvec2 __attribute__((ext_vector_type(2)));
union U2 { unsigned u; hvec2 h; __half2 hh; };

// DPP-based add within quads (VALU pipe)
template<int CTRL>
__device__ __forceinline__ float dpp_add(float v){
    int t = __builtin_amdgcn_update_dpp(0, __float_as_int(v), CTRL, 0xF, 0xF, true);
    return v + __int_as_float(t);
}

__device__ __forceinline__ float4 bfly_max(float4 v){
    #pragma unroll
    for (int k = 1; k < 64; k <<= 1){
        v.x = fmaxf(v.x, __shfl_xor(v.x, k, 64));
        v.y = fmaxf(v.y, __shfl_xor(v.y, k, 64));
        v.z = fmaxf(v.z, __shfl_xor(v.z, k, 64));
        v.w = fmaxf(v.w, __shfl_xor(v.w, k, 64));
    }
    return v;
}
__device__ __forceinline__ float4 bfly_sum(float4 v){
    #pragma unroll
    for (int k = 1; k < 64; k <<= 1){
        v.x += __shfl_xor(v.x, k, 64);
        v.y += __shfl_xor(v.y, k, 64);
        v.z += __shfl_xor(v.z, k, 64);
        v.w += __shfl_xor(v.w, k, 64);
    }
    return v;
}

// ---- K1: xl_h = half(x@Wl+bl) ; xr_h = half(x@Wr+br)  (32 rows / 256 thr) ----
__global__ void k_transform(const float* __restrict__ x,
                            const float* __restrict__ Wl, const float* __restrict__ bl,
                            const float* __restrict__ Wr, const float* __restrict__ br,
                            unsigned* __restrict__ xl_h, unsigned* __restrict__ xr_h, int N){
    __shared__ float xs[32][DIN];
    const int t  = threadIdx.x;
    const int c2 = t & 63;          // channel pair index
    const int rg = t >> 6;          // row group (8 rows each)
    const int base = blockIdx.x * 32;
    {
        const float4* xg = (const float4*)(x + (size_t)base * DIN);
        float4* xsv = (float4*)&xs[0][0];
        #pragma unroll
        for (int q = 0; q < 4; ++q){
            int idx = t + q * 256;
            int row = idx >> 5;
            xsv[idx] = (base + row < N) ? xg[idx] : make_float4(0.f,0.f,0.f,0.f);
        }
    }
    __syncthreads();
    const int j0 = 2 * c2;
    float al0[8], al1[8], ar0[8], ar1[8];
    {
        const float bl0 = bl[j0], bl1 = bl[j0 + 1];
        const float br0 = br[j0], br1 = br[j0 + 1];
        #pragma unroll
        for (int r = 0; r < 8; ++r){ al0[r]=bl0; al1[r]=bl1; ar0[r]=br0; ar1[r]=br1; }
    }
    const int r0 = rg * 8;
    const float2* Wl2 = (const float2*)Wl;
    const float2* Wr2 = (const float2*)Wr;
    #pragma unroll 2
    for (int k = 0; k < DIN; ++k){
        const float2 wl = Wl2[k * 64 + c2];
        const float2 wr = Wr2[k * 64 + c2];
        #pragma unroll
        for (int r = 0; r < 8; ++r){
            const float xv = xs[r0 + r][k];
            al0[r] = fmaf(xv, wl.x, al0[r]); al1[r] = fmaf(xv, wl.y, al1[r]);
            ar0[r] = fmaf(xv, wr.x, ar0[r]); ar1[r] = fmaf(xv, wr.y, ar1[r]);
        }
    }
    #pragma unroll
    for (int r = 0; r < 8; ++r){
        const int row = base + r0 + r;
        if (row < N){
            __half2 hl = __floats2half2_rn(al0[r], al1[r]);
            __half2 hr = __floats2half2_rn(ar0[r], ar1[r]);
            xl_h[(size_t)row * 64 + c2] = *(unsigned*)&hl;
            xr_h[(size_t)row * 64 + c2] = *(unsigned*)&hr;
        }
    }
}

// ---- histogram of dst; block 0 also preps att_h = half2(att * log2e) ----
__global__ void k_hist(const int* __restrict__ ei, unsigned* __restrict__ deg,
                       const float* __restrict__ att, unsigned* __restrict__ att_h, int E){
    int t = blockIdx.x * blockDim.x + threadIdx.x;
    if (blockIdx.x == 0 && threadIdx.x < 64){
        float2 a2 = ((const float2*)att)[threadIdx.x];
        __half2 h = __floats2half2_rn(a2.x * L2E, a2.y * L2E);
        att_h[threadIdx.x] = *(unsigned*)&h;
    }
    if (t < E) atomicAdd(&deg[ei[E + t]], 1u);
}

// ---- per-block sums of (deg+1) ----
__global__ void k_blocksum(const unsigned* __restrict__ deg, unsigned* __restrict__ bsum, int N){
    __shared__ unsigned lds[256];
    int t = threadIdx.x; int idx = blockIdx.x * 256 + t;
    lds[t] = (idx < N) ? (deg[idx] + 1u) : 0u; __syncthreads();
    for (int off = 128; off > 0; off >>= 1){ if (t < off) lds[t] += lds[t + off]; __syncthreads(); }
    if (t == 0) bsum[blockIdx.x] = lds[0];
}

// ---- exclusive scan of block sums (single block, NB<=1024) ----
__global__ void k_spine(const unsigned* __restrict__ bsum, unsigned* __restrict__ spine, int NB){
    __shared__ unsigned lds[1024];
    int t = threadIdx.x;
    unsigned v = (t < NB) ? bsum[t] : 0u;
    lds[t] = v; __syncthreads();
    unsigned acc = v;
    for (int off = 1; off < 1024; off <<= 1){
        unsigned add = (t >= off) ? lds[t - off] : 0u; __syncthreads();
        acc += add; lds[t] = acc; __syncthreads();
    }
    if (t < NB) spine[t] = acc - v;
}

// ---- scan -> row_start; also materialize self-loop slot 0 of each row ----
__global__ void k_scan_add(const unsigned* __restrict__ deg, const unsigned* __restrict__ spine,
                           unsigned* __restrict__ row_start,
                           int* __restrict__ csr_src, int* __restrict__ csr_dst, int N){
    __shared__ unsigned lds[256];
    int t = threadIdx.x; int idx = blockIdx.x * 256 + t;
    unsigned v = (idx < N) ? (deg[idx] + 1u) : 0u;
    lds[t] = v; __syncthreads();
    unsigned acc = v;
    for (int off = 1; off < 256; off <<= 1){
        unsigned add = (t >= off) ? lds[t - off] : 0u; __syncthreads();
        acc += add; lds[t] = acc; __syncthreads();
    }
    if (idx < N){
        unsigned r = spine[blockIdx.x] + acc - v;
        row_start[idx] = r;
        csr_src[r] = idx;          // self loop
        csr_dst[r] = idx;
        if (idx == N - 1) row_start[N] = spine[blockIdx.x] + acc;
    }
}

// ---- scatter edges into CSR slots >= 1 ----
__global__ void k_scatter(const int* __restrict__ ei, const unsigned* __restrict__ row_start,
                          unsigned* __restrict__ cursor, int* __restrict__ csr_src,
                          int* __restrict__ csr_dst, int E){
    int t = blockIdx.x * blockDim.x + threadIdx.x;
    if (t >= E) return;
    int dst = ei[E + t];
    unsigned pos = row_start[dst] + 1u + atomicAdd(&cursor[dst], 1u);
    csr_src[pos] = ei[t];
    csr_dst[pos] = dst;
}

// ---- edge-parallel scores: 16 lanes per edge, packed fp16, log2-domain ----
__global__ void k_score(const unsigned* __restrict__ xl_h, const unsigned* __restrict__ xr_h,
                        const int* __restrict__ csr_src, const int* __restrict__ csr_dst,
                        const unsigned* __restrict__ att_h, float* __restrict__ e_ws, int Et){
    const long long gtid = (long long)blockIdx.x * blockDim.x + threadIdx.x;
    const int wave = (int)(gtid >> 6);
    const int lane = threadIdx.x & 63;
    const int g = lane >> 4;           // edge within wave
    const int q = lane & 15;           // channel octet within edge
    const int slot = wave * 4 + g;
    if (slot >= Et) return;
    const int src = csr_src[slot];
    const int dst = csr_dst[slot];
    const uint4 xq = ((const uint4*)xl_h)[(size_t)src * 16 + q];
    const uint4 rq = ((const uint4*)xr_h)[(size_t)dst * 16 + q];
    const uint4 aq = ((const uint4*)att_h)[q];
    const hvec2 neg2 = {(_Float16)NEG, (_Float16)NEG};
    float s = 0.f;
    {
        U2 a, b, c;
        #pragma unroll
        for (int w = 0; w < 4; ++w){
            a.u = (&xq.x)[w]; b.u = (&rq.x)[w]; c.u = (&aq.x)[w];
            hvec2 z  = a.h + b.h;
            hvec2 r  = __builtin_elementwise_max(z, z * neg2);
#if __has_builtin(__builtin_amdgcn_fdot2)
            s = __builtin_amdgcn_fdot2(r, c.h, s, false);
#else
            U2 rr; rr.h = r; U2 cc; cc.h = c.h;
            float2 rf = __half22float2(rr.hh);
            float2 cf = __half22float2(cc.hh);
            s = fmaf(rf.x, cf.x, s); s = fmaf(rf.y, cf.y, s);
#endif
        }
    }
    // sum over the 4 lanes of each quad (quad == one head's 8-lane... 4-lane group)
    s = dpp_add<0xB1>(s);   // xor 1
    s = dpp_add<0x4E>(s);   // xor 2
    if ((q & 3) == 0) e_ws[(size_t)slot * 4 + (q >> 2)] = s;
}

// ---- node-parallel: softmax over CSR row + weighted aggregate + pool ----
__global__ void k_aggregate(const unsigned* __restrict__ xl_h, const float* __restrict__ e_ws,
                            const int* __restrict__ csr_src, const unsigned* __restrict__ row_start,
                            const float* __restrict__ bias, const int* __restrict__ batch,
                            unsigned* __restrict__ g_bits, int N){
    __shared__ float s_alpha[4][256];
    const int wid  = (int)(((long long)blockIdx.x * blockDim.x + threadIdx.x) >> 6);
    const int lane = threadIdx.x & 63;
    const int w    = threadIdx.x >> 6;
    if (wid >= N) return;
    const int i  = wid;
    const int rs = (int)row_start[i];
    const int re = (int)row_start[i + 1];
    const int deg = re - rs;
    const float4* eW = (const float4*)e_ws;
    const int h = lane >> 4;

    // phase A: per-head running (m, d) over 64-edge chunks
    float m0=-3.0e38f, m1=-3.0e38f, m2=-3.0e38f, m3=-3.0e38f;
    float d0=0.f, d1=0.f, d2=0.f, d3=0.f;
    for (int c0 = 0; c0 < deg; c0 += 64){
        const int e = c0 + lane;
        const bool v = e < deg;
        float4 s4 = v ? eW[rs + e] : make_float4(-3.0e38f,-3.0e38f,-3.0e38f,-3.0e38f);
        const float4 M = bfly_max(s4);
        float4 p;
        p.x = v ? exp2f(s4.x - M.x) : 0.f;
        p.y = v ? exp2f(s4.y - M.y) : 0.f;
        p.z = v ? exp2f(s4.z - M.z) : 0.f;
        p.w = v ? exp2f(s4.w - M.w) : 0.f;
        const float4 S = bfly_sum(p);
        float mn;
        mn = fmaxf(m0, M.x); d0 = d0 * exp2f(m0 - mn) + S.x * exp2f(M.x - mn); m0 = mn;
        mn = fmaxf(m1, M.y); d1 = d1 * exp2f(m1 - mn) + S.y * exp2f(M.y - mn); m1 = mn;
        mn = fmaxf(m2, M.z); d2 = d2 * exp2f(m2 - mn) + S.z * exp2f(M.z - mn); m2 = mn;
        mn = fmaxf(m3, M.w); d3 = d3 * exp2f(m3 - mn) + S.w * exp2f(M.w - mn); m3 = mn;
    }
    const float i0 = 1.f / (d0 + 1e-16f);
    const float i1 = 1.f / (d1 + 1e-16f);
    const float i2 = 1.f / (d2 + 1e-16f);
    const float i3 = 1.f / (d3 + 1e-16f);

    // phase B: alphas -> LDS, then gather-weighted accumulate
    float acc0x=0.f, acc0y=0.f, acc1x=0.f, acc1y=0.f;
    for (int c0 = 0; c0 < deg; c0 += 64){
        const int e = c0 + lane;
        const bool v = e < deg;
        float4 s4 = v ? eW[rs + e] : make_float4(0.f,0.f,0.f,0.f);
        const int sv = v ? csr_src[rs + e] : 0;
        float4 a4;
        a4.x = v ? exp2f(s4.x - m0) * i0 : 0.f;
        a4.y = v ? exp2f(s4.y - m1) * i1 : 0.f;
        a4.z = v ? exp2f(s4.z - m2) * i2 : 0.f;
        a4.w = v ? exp2f(s4.w - m3) * i3 : 0.f;
        ((float4*)&s_alpha[w][0])[lane] = a4;
        const int lim = (deg - c0 < 64) ? (deg - c0) : 64;
        int e2 = 0;
        for (; e2 + 3 < lim; e2 += 4){
            const int sA = __builtin_amdgcn_readlane(sv, e2);
            const int sB = __builtin_amdgcn_readlane(sv, e2 + 1);
            const int sC = __builtin_amdgcn_readlane(sv, e2 + 2);
            const int sD = __builtin_amdgcn_readlane(sv, e2 + 3);
            const unsigned hA = xl_h[(size_t)sA * 64 + lane];
            const unsigned hB = xl_h[(size_t)sB * 64 + lane];
            const unsigned hC = xl_h[(size_t)sC * 64 + lane];
            const unsigned hD = xl_h[(size_t)sD * 64 + lane];
            const float aA = s_alpha[w][(e2    ) * 4 + h];
            const float aB = s_alpha[w][(e2 + 1) * 4 + h];
            const float aC = s_alpha[w][(e2 + 2) * 4 + h];
            const float aD = s_alpha[w][(e2 + 3) * 4 + h];
            U2 u;
            u.u = hA; { float2 f = __half22float2(u.hh); acc0x = fmaf(aA, f.x, acc0x); acc0y = fmaf(aA, f.y, acc0y); }
            u.u = hB; { float2 f = __half22float2(u.hh); acc1x = fmaf(aB, f.x, acc1x); acc1y = fmaf(aB, f.y, acc1y); }
            u.u = hC; { float2 f = __half22float2(u.hh); acc0x = fmaf(aC, f.x, acc0x); acc0y = fmaf(aC, f.y, acc0y); }
            u.u = hD; { float2 f = __half22float2(u.hh); acc1x = fmaf(aD, f.x, acc1x); acc1y = fmaf(aD, f.y, acc1y); }
        }
        for (; e2 < lim; ++e2){
            const int sA = __builtin_amdgcn_readlane(sv, e2);
            const unsigned hA = xl_h[(size_t)sA * 64 + lane];
            const float aA = s_alpha[w][e2 * 4 + h];
            U2 u; u.u = hA;
            { float2 f = __half22float2(u.hh); acc0x = fmaf(aA, f.x, acc0x); acc0y = fmaf(aA, f.y, acc0y); }
        }
    }
    const float accx = acc0x + acc1x;
    const float accy = acc0y + acc1y;
    const float2 bz = ((const float2*)bias)[lane];
    const float h0 = fmaxf(accx + bz.x, 0.f);
    const float h1 = fmaxf(accy + bz.y, 0.f);
    const int g = batch[i];
    atomicMax(&g_bits[g * F + 2 * lane],     __float_as_uint(h0));
    atomicMax(&g_bits[g * F + 2 * lane + 1], __float_as_uint(h1));
}

// ---- dueling heads, one block (128 thr) per graph ----
__global__ void k_dueling(const float* __restrict__ g,
                          const float* __restrict__ Wq1, const float* __restrict__ bq1,
                          const float* __restrict__ Wq2, const float* __restrict__ bq2,
                          const float* __restrict__ Wv1, const float* __restrict__ bv1,
                          const float* __restrict__ Wv2, const float* __restrict__ bv2,
                          float* __restrict__ out){
    __shared__ float gs[F], red0[128], red1[128], red2[128];
    const int t = threadIdx.x, gi = blockIdx.x;
    gs[t] = g[gi * F + t];
    __syncthreads();
    float aq = bq1[t], av = bv1[t];
    for (int k = 0; k < F; ++k){
        aq = fmaf(gs[k], Wq1[k * HID + t], aq);
        av = fmaf(gs[k], Wv1[k * HID + t], av);
    }
    aq = aq > 0.f ? aq : 0.f;
    av = av > 0.f ? av : 0.f;
    red0[t] = aq * Wq2[t * 2 + 0];
    red1[t] = aq * Wq2[t * 2 + 1];
    red2[t] = av * Wv2[t];
    __syncthreads();
    for (int off = 64; off > 0; off >>= 1){
        if (t < off){ red0[t] += red0[t + off]; red1[t] += red1[t + off]; red2[t] += red2[t + off]; }
        __syncthreads();
    }
    if (t == 0){
        const float q0 = red0[0] + bq2[0];
        const float q1 = red1[0] + bq2[1];
        const float v  = red2[0] + bv2[0];
        out[gi * 2 + 0] = 0.5f * (q0 - q1) + v;
        out[gi * 2 + 1] = 0.5f * (q1 - q0) + v;
    }
}

extern "C" void kernel_launch(void* const* d_in, const int* in_sizes, int n_in,
                              void* d_out, int out_size, void* d_ws, size_t ws_size,
                              hipStream_t stream) {
    const float* x    = (const float*)d_in[0];
    const float* Wl   = (const float*)d_in[1];
    const float* bl   = (const float*)d_in[2];
    const float* Wr   = (const float*)d_in[3];
    const float* br   = (const float*)d_in[4];
    const float* att  = (const float*)d_in[5];
    const float* bias = (const float*)d_in[6];
    const float* Wq1  = (const float*)d_in[7];
    const float* bq1  = (const float*)d_in[8];
    const float* Wq2  = (const float*)d_in[9];
    const float* bq2  = (const float*)d_in[10];
    const float* Wv1  = (const float*)d_in[11];
    const float* bv1  = (const float*)d_in[12];
    const float* Wv2  = (const float*)d_in[13];
    const float* bv2  = (const float*)d_in[14];
    const int*   ei   = (const int*)d_in[15];
    const int*   batch= (const int*)d_in[16];
    float* out = (float*)d_out;

    const int N  = in_sizes[0] / DIN;
    const int E  = in_sizes[15] / 2;
    const int Et = E + N;
    const int Gg = out_size / 2;
    const int GF = Gg * F;
    const int NB = (N + 255) / 256;

    // workspace layout (unsigned words; e_ws 16B-aligned)
    unsigned* xl_h      = (unsigned*)d_ws;                 // N*64
    unsigned* xr_h      = xl_h + (size_t)N * 64;           // N*64
    unsigned* att_h     = xr_h + (size_t)N * 64;           // 64
    float*    e_ws      = (float*)(att_h + 64);            // Et*4
    unsigned* deg       = (unsigned*)(e_ws + (size_t)Et*4);// N      --+
    unsigned* cursor    = deg + N;                         // N        | zeroed
    unsigned* g_bits    = cursor + N;                      // GF     --+
    unsigned* row_start = g_bits + GF;                     // N+1
    unsigned* bsum      = row_start + N + 1;               // NB
    unsigned* spine     = bsum + NB;                       // NB
    int*      csr_src   = (int*)(spine + NB);              // Et
    int*      csr_dst   = csr_src + Et;                    // Et

    k_transform<<<(N + 31) / 32, 256, 0, stream>>>(x, Wl, bl, Wr, br, xl_h, xr_h, N);
    hipMemsetAsync(deg, 0, (size_t)(2 * N + GF) * sizeof(unsigned), stream);
    k_hist<<<(E + 255) / 256, 256, 0, stream>>>(ei, deg, att, att_h, E);
    k_blocksum<<<NB, 256, 0, stream>>>(deg, bsum, N);
    k_spine<<<1, 1024, 0, stream>>>(bsum, spine, NB);
    k_scan_add<<<NB, 256, 0, stream>>>(deg, spine, row_start, csr_src, csr_dst, N);
    k_scatter<<<(E + 255) / 256, 256, 0, stream>>>(ei, row_start, cursor, csr_src, csr_dst, E);
    {
        long long waves = (Et + 3) / 4;
        long long thr = waves * 64;
        k_score<<<(unsigned)((thr + 255) / 256), 256, 0, stream>>>(
            xl_h, xr_h, csr_src, csr_dst, att_h, e_ws, Et);
    }
    {
        long long thr = (long long)N * 64;
        k_aggregate<<<(unsigned)((thr + 255) / 256), 256, 0, stream>>>(
            xl_h, e_ws, csr_src, row_start, bias, batch, g_bits, N);
    }
    k_dueling<<<Gg, 128, 0, stream>>>((const float*)g_bits, Wq1, bq1, Wq2, bq2,
                                      Wv1, bv1, Wv2, bv2, out);
}